// Round 4
// baseline (524.828 us; speedup 1.0000x reference)
//
#include <hip/hip_runtime.h>
#include <cstdint>

#define FEAT 4096
#define DIN  64
#define HS   32
#define NL   8
#define TT   300
#define BB   64
#define G4   128           // 4*HS
#define MROWS (BB*TT)      // 19200
#define KS    4            // K-split for big GEMM
#define KSLICE (FEAT/KS)   // 1024
#define BK    64
#define NCHUNK (KSLICE/BK) // 16
#define NSUP  (TT/2 + NL - 1)  // 157 supersteps

typedef __bf16 bf16x8 __attribute__((ext_vector_type(8)));
typedef float  f32x4  __attribute__((ext_vector_type(4)));
typedef unsigned short u16x8 __attribute__((ext_vector_type(8)));

__device__ __forceinline__ float sigm(float x){ return __fdividef(1.f, 1.f + __expf(-x)); }
__device__ __forceinline__ float tanh_f(float x){ return __fdividef(2.f, 1.f + __expf(-2.f*x)) - 1.f; }

__device__ __forceinline__ float2 pkfma(float2 w, float h, float2 c){
    return make_float2(fmaf(w.x, h, c.x), fmaf(w.y, h, c.y));
}
__device__ __forceinline__ float2 add2(float2 a, float2 b){
    return make_float2(a.x + b.x, a.y + b.y);
}

__device__ __forceinline__ unsigned short bf16_rne(float f){
    uint32_t u = __float_as_uint(f);
    return (unsigned short)((u + 0x7FFFu + ((u >> 16) & 1u)) >> 16);
}

// ---------------------------------------------------------------------------
// Prep: split W0 [64][4096] fp32 into bf16 hi/lo planes (RNE + residual).
// ---------------------------------------------------------------------------
__global__ __launch_bounds__(256) void w0split(const float* __restrict__ W0,
                                               unsigned short* __restrict__ wh,
                                               unsigned short* __restrict__ wl)
{
    const int i = (blockIdx.x * 256 + threadIdx.x) * 4;
    float4 v = *(const float4*)(W0 + i);
    float f[4] = {v.x, v.y, v.z, v.w};
    unsigned short hh[4], ll[4];
    #pragma unroll
    for (int j = 0; j < 4; ++j) {
        unsigned short h = bf16_rne(f[j]);
        float fh = __uint_as_float((uint32_t)h << 16);
        hh[j] = h;
        ll[j] = bf16_rne(f[j] - fh);
    }
    *(ushort4*)(wh + i) = make_ushort4(hh[0], hh[1], hh[2], hh[3]);
    *(ushort4*)(wl + i) = make_ushort4(ll[0], ll[1], ll[2], ll[3]);
}

// ---------------------------------------------------------------------------
// Kernel 1: h1pre partials = x @ W0^T, bf16x3-split MFMA, split-K. (unchanged)
// ---------------------------------------------------------------------------
__global__ __launch_bounds__(256, 2) void fc_gemm1(
    const float* __restrict__ x,
    const unsigned short* __restrict__ wh,
    const unsigned short* __restrict__ wl,
    float* __restrict__ part)
{
    __shared__ __align__(16) unsigned short xh[2][64][64];
    __shared__ __align__(16) unsigned short xl[2][64][64];
    __shared__ __align__(16) unsigned short wh_s[2][64][64];
    __shared__ __align__(16) unsigned short wl_s[2][64][64];

    const int t   = threadIdx.x;
    const int l   = t & 63;
    const int w   = t >> 6;
    const int rbb = (w >> 1) * 32;
    const int cbb = (w & 1) * 32;
    const int r0  = blockIdx.x * 64;
    const int kb0 = blockIdx.y * KSLICE;

    const int srow = t >> 3;
    const int sg   = t & 7;

    f32x4 acc[2][2];
    #pragma unroll
    for (int i = 0; i < 2; ++i)
        #pragma unroll
        for (int j = 0; j < 2; ++j)
            acc[i][j] = (f32x4){0.f, 0.f, 0.f, 0.f};

    float4 xr[2][2];
    uint4  w0h[2], w0l[2];

    auto LOAD = [&](int c) {
        const float* xb = x + (size_t)r0 * FEAT + kb0 + c * BK;
        xr[0][0] = *(const float4*)(xb + (size_t)srow * FEAT + sg * 8);
        xr[0][1] = *(const float4*)(xb + (size_t)srow * FEAT + sg * 8 + 4);
        xr[1][0] = *(const float4*)(xb + (size_t)(srow + 32) * FEAT + sg * 8);
        xr[1][1] = *(const float4*)(xb + (size_t)(srow + 32) * FEAT + sg * 8 + 4);
        const int wo = kb0 + c * BK + sg * 8;
        w0h[0] = *(const uint4*)(wh + (size_t)srow * FEAT + wo);
        w0h[1] = *(const uint4*)(wh + (size_t)(srow + 32) * FEAT + wo);
        w0l[0] = *(const uint4*)(wl + (size_t)srow * FEAT + wo);
        w0l[1] = *(const uint4*)(wl + (size_t)(srow + 32) * FEAT + wo);
    };

    auto STORE = [&](int c) {
        const int buf = c & 1;
        #pragma unroll
        for (int j = 0; j < 2; ++j) {
            const int row = srow + j * 32;
            const int gsw = (sg ^ (row & 7)) * 8;
            float f0[8] = {xr[j][0].x, xr[j][0].y, xr[j][0].z, xr[j][0].w,
                           xr[j][1].x, xr[j][1].y, xr[j][1].z, xr[j][1].w};
            u16x8 vh, vl;
            #pragma unroll
            for (int i = 0; i < 8; ++i) {
                uint32_t u  = __float_as_uint(f0[i]);
                uint32_t rh = (u + 0x7FFFu + ((u >> 16) & 1u)) >> 16;
                vh[i] = (unsigned short)rh;
                float fl = f0[i] - __uint_as_float(rh << 16);
                uint32_t u2 = __float_as_uint(fl);
                vl[i] = (unsigned short)((u2 + 0x7FFFu + ((u2 >> 16) & 1u)) >> 16);
            }
            *(u16x8*)&xh[buf][row][gsw] = vh;
            *(u16x8*)&xl[buf][row][gsw] = vl;
            *(uint4*)&wh_s[buf][row][gsw] = w0h[j];
            *(uint4*)&wl_s[buf][row][gsw] = w0l[j];
        }
    };

    auto COMPUTE = [&](int buf) {
        #pragma unroll
        for (int kstep = 0; kstep < 2; ++kstep) {
            const int gA = kstep * 4 + (l >> 4);
            bf16x8 Ah[2], Al[2], Bh[2], Bl[2];
            #pragma unroll
            for (int rf = 0; rf < 2; ++rf) {
                const int ra  = rbb + rf * 16 + (l & 15);
                const int off = (gA ^ (ra & 7)) * 8;
                Ah[rf] = __builtin_bit_cast(bf16x8, *(const u16x8*)&xh[buf][ra][off]);
                Al[rf] = __builtin_bit_cast(bf16x8, *(const u16x8*)&xl[buf][ra][off]);
            }
            #pragma unroll
            for (int cf = 0; cf < 2; ++cf) {
                const int cb  = cbb + cf * 16 + (l & 15);
                const int off = (gA ^ (cb & 7)) * 8;
                Bh[cf] = __builtin_bit_cast(bf16x8, *(const u16x8*)&wh_s[buf][cb][off]);
                Bl[cf] = __builtin_bit_cast(bf16x8, *(const u16x8*)&wl_s[buf][cb][off]);
            }
            #pragma unroll
            for (int rf = 0; rf < 2; ++rf)
                #pragma unroll
                for (int cf = 0; cf < 2; ++cf) {
                    acc[rf][cf] = __builtin_amdgcn_mfma_f32_16x16x32_bf16(Ah[rf], Bh[cf], acc[rf][cf], 0, 0, 0);
                    acc[rf][cf] = __builtin_amdgcn_mfma_f32_16x16x32_bf16(Al[rf], Bh[cf], acc[rf][cf], 0, 0, 0);
                    acc[rf][cf] = __builtin_amdgcn_mfma_f32_16x16x32_bf16(Ah[rf], Bl[cf], acc[rf][cf], 0, 0, 0);
                }
        }
    };

    LOAD(0);
    for (int c = 0; c < NCHUNK; ++c) {
        STORE(c);
        if (c + 1 < NCHUNK) LOAD(c + 1);
        asm volatile("s_waitcnt lgkmcnt(0)" ::: "memory");
        __builtin_amdgcn_s_barrier();
        COMPUTE(c & 1);
    }

    #pragma unroll
    for (int rf = 0; rf < 2; ++rf)
        #pragma unroll
        for (int cf = 0; cf < 2; ++cf)
            #pragma unroll
            for (int r = 0; r < 4; ++r) {
                const int row = r0 + rbb + rf * 16 + (l >> 4) * 4 + r;
                const int col = cbb + cf * 16 + (l & 15);
                part[((size_t)blockIdx.y * MROWS + row) * 64 + col] = acc[rf][cf][r];
            }
}

// ---------------------------------------------------------------------------
// Kernel 2: reduce partials -> relu(h1) -> h2 -> gx0 (unchanged)
// ---------------------------------------------------------------------------
__global__ __launch_bounds__(256) void fc_tail(
    const float* __restrict__ part, const float* __restrict__ b0,
    const float* __restrict__ W1, const float* __restrict__ b1,
    const float* __restrict__ Wih0,
    const float* __restrict__ bih, const float* __restrict__ bhh,
    float* __restrict__ gx0)
{
    __shared__ __align__(16) float h1s[64][68];
    __shared__ __align__(16) float h2s[64][68];

    const int tid = threadIdx.x;
    const int tc  = tid & 15;
    const int tr  = tid >> 4;
    const int r0  = blockIdx.x * 64;

    {
        const int row = tid >> 2;
        const int c0  = (tid & 3) * 16;
        float4 s[4];
        #pragma unroll
        for (int i = 0; i < 4; ++i)
            s[i] = *(const float4*)(part + ((size_t)(r0 + row)) * 64 + c0 + 4 * i);
        #pragma unroll
        for (int ks = 1; ks < KS; ++ks)
            #pragma unroll
            for (int i = 0; i < 4; ++i) {
                float4 v = *(const float4*)(part + ((size_t)ks * MROWS + r0 + row) * 64 + c0 + 4 * i);
                s[i].x += v.x; s[i].y += v.y; s[i].z += v.z; s[i].w += v.w;
            }
        #pragma unroll
        for (int i = 0; i < 4; ++i) {
            float4 bv = *(const float4*)(b0 + c0 + 4 * i);
            float4 o;
            o.x = fmaxf(s[i].x + bv.x, 0.f);
            o.y = fmaxf(s[i].y + bv.y, 0.f);
            o.z = fmaxf(s[i].z + bv.z, 0.f);
            o.w = fmaxf(s[i].w + bv.w, 0.f);
            *(float4*)&h1s[row][c0 + 4 * i] = o;
        }
    }
    __syncthreads();

    float acc2[4][4] = {};
    #pragma unroll
    for (int k4 = 0; k4 < 16; ++k4) {
        const int k = k4 * 4;
        float4 a[4], wv[4];
        #pragma unroll
        for (int i = 0; i < 4; ++i) a[i] = *(const float4*)&h1s[tr * 4 + i][k];
        #pragma unroll
        for (int j = 0; j < 4; ++j) wv[j] = *(const float4*)(W1 + (size_t)(tc * 4 + j) * DIN + k);
        #pragma unroll
        for (int i = 0; i < 4; ++i)
            #pragma unroll
            for (int j = 0; j < 4; ++j)
                acc2[i][j] += a[i].x * wv[j].x + a[i].y * wv[j].y + a[i].z * wv[j].z + a[i].w * wv[j].w;
    }
    __syncthreads();
    #pragma unroll
    for (int i = 0; i < 4; ++i)
        #pragma unroll
        for (int j = 0; j < 4; ++j)
            h2s[tr * 4 + i][tc * 4 + j] = acc2[i][j] + b1[tc * 4 + j];
    __syncthreads();

    #pragma unroll
    for (int p = 0; p < 2; ++p) {
        float acc3[4][4] = {};
        #pragma unroll
        for (int k4 = 0; k4 < 16; ++k4) {
            const int k = k4 * 4;
            float4 a[4], wv[4];
            #pragma unroll
            for (int i = 0; i < 4; ++i) a[i] = *(const float4*)&h2s[tr * 4 + i][k];
            #pragma unroll
            for (int j = 0; j < 4; ++j) wv[j] = *(const float4*)(Wih0 + (size_t)(p * 64 + tc * 4 + j) * DIN + k);
            #pragma unroll
            for (int i = 0; i < 4; ++i)
                #pragma unroll
                for (int j = 0; j < 4; ++j)
                    acc3[i][j] += a[i].x * wv[j].x + a[i].y * wv[j].y + a[i].z * wv[j].z + a[i].w * wv[j].w;
        }
        const int g0 = p * 64 + tc * 4;
        #pragma unroll
        for (int i = 0; i < 4; ++i) {
            float4 ov;
            ov.x = acc3[i][0] + bih[g0 + 0] + bhh[g0 + 0];
            ov.y = acc3[i][1] + bih[g0 + 1] + bhh[g0 + 1];
            ov.z = acc3[i][2] + bih[g0 + 2] + bhh[g0 + 2];
            ov.w = acc3[i][3] + bih[g0 + 3] + bhh[g0 + 3];
            *(float4*)(gx0 + (size_t)(r0 + tr * 4 + i) * G4 + g0) = ov;
        }
    }
}

// ---------------------------------------------------------------------------
// Kernel 3: wavefront-pipelined LSTM, TWO timesteps per superstep.
// Wave l at superstep s handles t0 = 2(s-l), t1 = t0+1.
// r2-style __syncthreads per superstep (known good); float2-packed weights
// (v_pk_fma_f32); shfl_xor(32) gate redistribution (proven correct in r3).
// ---------------------------------------------------------------------------
__global__ __launch_bounds__(512, 2) void lstm_all(
    const float* __restrict__ gx0,
    const float* __restrict__ Wih, const float* __restrict__ Whh,
    const float* __restrict__ bih, const float* __restrict__ bhh,
    const float* __restrict__ Wfc1, const float* __restrict__ bfc1,
    const float* __restrict__ Wfc2, const float* __restrict__ bfc2,
    float* __restrict__ out)
{
    const int b    = blockIdx.x;
    const int tid  = threadIdx.x;
    const int l    = tid >> 6;
    const int lane = tid & 63;
    const int q0   = lane;         // gate rows owned: q0 (i|f half), q1 (g|o half)
    const int q1   = lane + 64;

    __shared__ __align__(16) float hbuf[NL][2][2][HS];  // [layer][s parity][sub-t][h]
    __shared__ __align__(16) float h7[TT][HS];
    __shared__ float red[NL];

    // packed weights: w2[k] = {W[q0][k], W[q1][k]}
    float2 whh2[HS], wih2[HS];
    {
        const float* whhl = Whh + (size_t)l * G4 * HS;
        const float* wihl = Wih + (size_t)(l > 0 ? l - 1 : 0) * G4 * HS;
        #pragma unroll
        for (int k = 0; k < HS; k += 4) {
            float4 a0 = *(const float4*)(whhl + q0 * HS + k);
            float4 a1 = *(const float4*)(whhl + q1 * HS + k);
            whh2[k+0] = make_float2(a0.x, a1.x);
            whh2[k+1] = make_float2(a0.y, a1.y);
            whh2[k+2] = make_float2(a0.z, a1.z);
            whh2[k+3] = make_float2(a0.w, a1.w);
            float4 u0 = *(const float4*)(wihl + q0 * HS + k);
            float4 u1 = *(const float4*)(wihl + q1 * HS + k);
            wih2[k+0] = make_float2(u0.x, u1.x);
            wih2[k+1] = make_float2(u0.y, u1.y);
            wih2[k+2] = make_float2(u0.z, u1.z);
            wih2[k+3] = make_float2(u0.w, u1.w);
        }
    }
    const float2 bias2 = (l > 0)
        ? make_float2(bih[l*G4 + q0] + bhh[l*G4 + q0], bih[l*G4 + q1] + bhh[l*G4 + q1])
        : make_float2(0.f, 0.f);

    float c_state = 0.f;   // all 64 lanes, index m = lane & 31 (redundant halves)

    const float* gxb = gx0 + (size_t)b * TT * G4;
    float2 pg0 = make_float2(0.f, 0.f), pg1 = pg0;   // prefetched gx for t0, t1
    if (l == 0) {
        pg0 = make_float2(gxb[q0],      gxb[q1]);
        pg1 = make_float2(gxb[G4 + q0], gxb[G4 + q1]);
    }

    for (int s = 0; s < NSUP; ++s) {
        const int t0 = 2 * (s - l);                    // wave-uniform
        if (0 <= t0 && t0 < TT) {
            float2 g0, g1;
            if (l == 0) {
                g0 = pg0; g1 = pg1;
                const int tn = t0 + 2;
                if (tn < TT) {
                    pg0 = make_float2(gxb[(size_t)tn * G4 + q0],       gxb[(size_t)tn * G4 + q1]);
                    pg1 = make_float2(gxb[(size_t)(tn + 1) * G4 + q0], gxb[(size_t)(tn + 1) * G4 + q1]);
                }
            }

            // ---- input terms for both timesteps (independent of t0 chain) ----
            float2 P0[2] = {make_float2(0,0), make_float2(0,0)};
            float2 P1[2] = {make_float2(0,0), make_float2(0,0)};
            if (l > 0) {
                const float4* hp0 = (const float4*)hbuf[l-1][(s-1) & 1][0];
                const float4* hp1 = (const float4*)hbuf[l-1][(s-1) & 1][1];
                #pragma unroll
                for (int k4 = 0; k4 < 8; ++k4) {
                    float4 v = hp0[k4];
                    P0[0] = pkfma(wih2[4*k4+0], v.x, P0[0]);
                    P0[1] = pkfma(wih2[4*k4+1], v.y, P0[1]);
                    P0[0] = pkfma(wih2[4*k4+2], v.z, P0[0]);
                    P0[1] = pkfma(wih2[4*k4+3], v.w, P0[1]);
                }
                #pragma unroll
                for (int k4 = 0; k4 < 8; ++k4) {
                    float4 v = hp1[k4];
                    P1[0] = pkfma(wih2[4*k4+0], v.x, P1[0]);
                    P1[1] = pkfma(wih2[4*k4+1], v.y, P1[1]);
                    P1[0] = pkfma(wih2[4*k4+2], v.z, P1[0]);
                    P1[1] = pkfma(wih2[4*k4+3], v.w, P1[1]);
                }
            }

            // ---- t0: recurrent term from h[t0-1] (prev superstep sub-t 1) ----
            float2 R[2] = {make_float2(0,0), make_float2(0,0)};
            if (t0 > 0) {
                const float4* hs = (const float4*)hbuf[l][(s-1) & 1][1];
                #pragma unroll
                for (int k4 = 0; k4 < 8; ++k4) {
                    float4 v = hs[k4];
                    R[0] = pkfma(whh2[4*k4+0], v.x, R[0]);
                    R[1] = pkfma(whh2[4*k4+1], v.y, R[1]);
                    R[0] = pkfma(whh2[4*k4+2], v.z, R[0]);
                    R[1] = pkfma(whh2[4*k4+3], v.w, R[1]);
                }
            }
            float2 gate = add2(add2(R[0], R[1]),
                               (l == 0) ? g0 : add2(bias2, add2(P0[0], P0[1])));

            // redistribute: lane m: {i,g}; lane m+32: {f,o}
            {
                const float sw0 = __shfl_xor(gate.x, 32, 64);
                const float sw1 = __shfl_xor(gate.y, 32, 64);
                const bool lo = (lane < 32);
                const float gi = lo ? gate.x : sw0;
                const float gf = lo ? sw0 : gate.x;
                const float gg = lo ? gate.y : sw1;
                const float go = lo ? sw1 : gate.y;
                c_state = sigm(gf) * c_state + sigm(gi) * tanh_f(gg);
                const float hv = sigm(go) * tanh_f(c_state);
                if (lane < HS) {
                    hbuf[l][s & 1][0][lane] = hv;
                    if (l == NL - 1) h7[t0][lane] = hv;
                }
            }
            // in-wave visibility of our own h[t0] write
            asm volatile("s_waitcnt lgkmcnt(0)");

            // ---- t1: recurrent term from h[t0] just written ----
            float2 R1[2] = {make_float2(0,0), make_float2(0,0)};
            {
                const float4* hs = (const float4*)hbuf[l][s & 1][0];
                #pragma unroll
                for (int k4 = 0; k4 < 8; ++k4) {
                    float4 v = hs[k4];
                    R1[0] = pkfma(whh2[4*k4+0], v.x, R1[0]);
                    R1[1] = pkfma(whh2[4*k4+1], v.y, R1[1]);
                    R1[0] = pkfma(whh2[4*k4+2], v.z, R1[0]);
                    R1[1] = pkfma(whh2[4*k4+3], v.w, R1[1]);
                }
            }
            float2 gate1 = add2(add2(R1[0], R1[1]),
                                (l == 0) ? g1 : add2(bias2, add2(P1[0], P1[1])));
            {
                const float sw0 = __shfl_xor(gate1.x, 32, 64);
                const float sw1 = __shfl_xor(gate1.y, 32, 64);
                const bool lo = (lane < 32);
                const float gi = lo ? gate1.x : sw0;
                const float gf = lo ? sw0 : gate1.x;
                const float gg = lo ? gate1.y : sw1;
                const float go = lo ? sw1 : gate1.y;
                c_state = sigm(gf) * c_state + sigm(gi) * tanh_f(gg);
                const float hv = sigm(go) * tanh_f(c_state);
                if (lane < HS) {
                    hbuf[l][s & 1][1][lane] = hv;
                    if (l == NL - 1) h7[t0 + 1][lane] = hv;
                }
            }
        }
        __syncthreads();
    }

    // ---- fused fc1 (over H) + fc2 (over T) ----
    float part = 0.f;
    for (int t = tid; t < TT; t += 512) {
        float st = 0.f;
        #pragma unroll
        for (int j = 0; j < HS; ++j) st = fmaf(h7[t][j], Wfc1[j], st);
        part += (st + bfc1[0]) * Wfc2[t];
    }
    #pragma unroll
    for (int off = 32; off >= 1; off >>= 1) part += __shfl_down(part, off, 64);
    if (lane == 0) red[l] = part;
    __syncthreads();
    if (tid == 0) {
        float tot = 0.f;
        #pragma unroll
        for (int w = 0; w < NL; ++w) tot += red[w];
        out[b] = tot + bfc2[0];
    }
}

// ---------------------------------------------------------------------------
extern "C" void kernel_launch(void* const* d_in, const int* in_sizes, int n_in,
                              void* d_out, int out_size, void* d_ws, size_t ws_size,
                              hipStream_t stream) {
    const float* x    = (const float*)d_in[0];
    const float* W0   = (const float*)d_in[1];
    const float* b0   = (const float*)d_in[2];
    const float* W1   = (const float*)d_in[3];
    const float* b1   = (const float*)d_in[4];
    const float* Wih0 = (const float*)d_in[5];
    const float* Wih  = (const float*)d_in[6];
    const float* Whh  = (const float*)d_in[7];
    const float* bih  = (const float*)d_in[8];
    const float* bhh  = (const float*)d_in[9];
    const float* Wfc1 = (const float*)d_in[10];
    const float* bfc1 = (const float*)d_in[11];
    const float* Wfc2 = (const float*)d_in[12];
    const float* bfc2 = (const float*)d_in[13];

    char* wsb = (char*)d_ws;
    float*          gx0 = (float*)wsb;                                   // 9,830,400 B
    unsigned short* wh  = (unsigned short*)(wsb + 9830400);              //   524,288 B
    unsigned short* wl  = (unsigned short*)(wsb + 9830400 + 524288);     //   524,288 B
    float*          prt = (float*)(wsb + 9830400 + 1048576);             // 19,660,800 B

    w0split <<<256, 256, 0, stream>>>(W0, wh, wl);
    fc_gemm1<<<dim3(MROWS / 64, KS), 256, 0, stream>>>(x, wh, wl, prt);
    fc_tail <<<MROWS / 64, 256, 0, stream>>>(prt, b0, W1, b1, Wih0, bih, bhh, gx0);
    lstm_all<<<BB, 512, 0, stream>>>(gx0, Wih, Whh, bih, bhh, Wfc1, bfc1, Wfc2, bfc2,
                                     (float*)d_out);
}

// Round 5
// 474.806 us; speedup vs baseline: 1.1054x; 1.1054x over previous
//
#include <hip/hip_runtime.h>
#include <cstdint>

#define FEAT 4096
#define DIN  64
#define HS   32
#define NL   8
#define TT   300
#define BB   64
#define G4   128           // 4*HS
#define MROWS (BB*TT)      // 19200
#define KS    4            // K-split for big GEMM
#define KSLICE (FEAT/KS)   // 1024
#define BK    64
#define NCHUNK (KSLICE/BK) // 16

typedef __bf16 bf16x8 __attribute__((ext_vector_type(8)));
typedef float  f32x4  __attribute__((ext_vector_type(4)));
typedef unsigned short u16x8 __attribute__((ext_vector_type(8)));

__device__ __forceinline__ float sigm(float x){ return __fdividef(1.f, 1.f + __expf(-x)); }
__device__ __forceinline__ float tanh_f(float x){ return __fdividef(2.f, 1.f + __expf(-2.f*x)) - 1.f; }

__device__ __forceinline__ float2 pkfma(float2 w, float h, float2 c){
    return make_float2(fmaf(w.x, h, c.x), fmaf(w.y, h, c.y));
}
__device__ __forceinline__ float2 add2(float2 a, float2 b){
    return make_float2(a.x + b.x, a.y + b.y);
}

__device__ __forceinline__ unsigned short bf16_rne(float f){
    uint32_t u = __float_as_uint(f);
    return (unsigned short)((u + 0x7FFFu + ((u >> 16) & 1u)) >> 16);
}

// ---------------------------------------------------------------------------
// Prep: split W0 [64][4096] fp32 into bf16 hi/lo planes (RNE + residual).
// ---------------------------------------------------------------------------
__global__ __launch_bounds__(256) void w0split(const float* __restrict__ W0,
                                               unsigned short* __restrict__ wh,
                                               unsigned short* __restrict__ wl)
{
    const int i = (blockIdx.x * 256 + threadIdx.x) * 4;
    float4 v = *(const float4*)(W0 + i);
    float f[4] = {v.x, v.y, v.z, v.w};
    unsigned short hh[4], ll[4];
    #pragma unroll
    for (int j = 0; j < 4; ++j) {
        unsigned short h = bf16_rne(f[j]);
        float fh = __uint_as_float((uint32_t)h << 16);
        hh[j] = h;
        ll[j] = bf16_rne(f[j] - fh);
    }
    *(ushort4*)(wh + i) = make_ushort4(hh[0], hh[1], hh[2], hh[3]);
    *(ushort4*)(wl + i) = make_ushort4(ll[0], ll[1], ll[2], ll[3]);
}

// ---------------------------------------------------------------------------
// Kernel 1: h1pre partials = x @ W0^T, bf16x3-split MFMA, split-K. (unchanged)
// ---------------------------------------------------------------------------
__global__ __launch_bounds__(256, 2) void fc_gemm1(
    const float* __restrict__ x,
    const unsigned short* __restrict__ wh,
    const unsigned short* __restrict__ wl,
    float* __restrict__ part)
{
    __shared__ __align__(16) unsigned short xh[2][64][64];
    __shared__ __align__(16) unsigned short xl[2][64][64];
    __shared__ __align__(16) unsigned short wh_s[2][64][64];
    __shared__ __align__(16) unsigned short wl_s[2][64][64];

    const int t   = threadIdx.x;
    const int l   = t & 63;
    const int w   = t >> 6;
    const int rbb = (w >> 1) * 32;
    const int cbb = (w & 1) * 32;
    const int r0  = blockIdx.x * 64;
    const int kb0 = blockIdx.y * KSLICE;

    const int srow = t >> 3;
    const int sg   = t & 7;

    f32x4 acc[2][2];
    #pragma unroll
    for (int i = 0; i < 2; ++i)
        #pragma unroll
        for (int j = 0; j < 2; ++j)
            acc[i][j] = (f32x4){0.f, 0.f, 0.f, 0.f};

    float4 xr[2][2];
    uint4  w0h[2], w0l[2];

    auto LOAD = [&](int c) {
        const float* xb = x + (size_t)r0 * FEAT + kb0 + c * BK;
        xr[0][0] = *(const float4*)(xb + (size_t)srow * FEAT + sg * 8);
        xr[0][1] = *(const float4*)(xb + (size_t)srow * FEAT + sg * 8 + 4);
        xr[1][0] = *(const float4*)(xb + (size_t)(srow + 32) * FEAT + sg * 8);
        xr[1][1] = *(const float4*)(xb + (size_t)(srow + 32) * FEAT + sg * 8 + 4);
        const int wo = kb0 + c * BK + sg * 8;
        w0h[0] = *(const uint4*)(wh + (size_t)srow * FEAT + wo);
        w0h[1] = *(const uint4*)(wh + (size_t)(srow + 32) * FEAT + wo);
        w0l[0] = *(const uint4*)(wl + (size_t)srow * FEAT + wo);
        w0l[1] = *(const uint4*)(wl + (size_t)(srow + 32) * FEAT + wo);
    };

    auto STORE = [&](int c) {
        const int buf = c & 1;
        #pragma unroll
        for (int j = 0; j < 2; ++j) {
            const int row = srow + j * 32;
            const int gsw = (sg ^ (row & 7)) * 8;
            float f0[8] = {xr[j][0].x, xr[j][0].y, xr[j][0].z, xr[j][0].w,
                           xr[j][1].x, xr[j][1].y, xr[j][1].z, xr[j][1].w};
            u16x8 vh, vl;
            #pragma unroll
            for (int i = 0; i < 8; ++i) {
                uint32_t u  = __float_as_uint(f0[i]);
                uint32_t rh = (u + 0x7FFFu + ((u >> 16) & 1u)) >> 16;
                vh[i] = (unsigned short)rh;
                float fl = f0[i] - __uint_as_float(rh << 16);
                uint32_t u2 = __float_as_uint(fl);
                vl[i] = (unsigned short)((u2 + 0x7FFFu + ((u2 >> 16) & 1u)) >> 16);
            }
            *(u16x8*)&xh[buf][row][gsw] = vh;
            *(u16x8*)&xl[buf][row][gsw] = vl;
            *(uint4*)&wh_s[buf][row][gsw] = w0h[j];
            *(uint4*)&wl_s[buf][row][gsw] = w0l[j];
        }
    };

    auto COMPUTE = [&](int buf) {
        #pragma unroll
        for (int kstep = 0; kstep < 2; ++kstep) {
            const int gA = kstep * 4 + (l >> 4);
            bf16x8 Ah[2], Al[2], Bh[2], Bl[2];
            #pragma unroll
            for (int rf = 0; rf < 2; ++rf) {
                const int ra  = rbb + rf * 16 + (l & 15);
                const int off = (gA ^ (ra & 7)) * 8;
                Ah[rf] = __builtin_bit_cast(bf16x8, *(const u16x8*)&xh[buf][ra][off]);
                Al[rf] = __builtin_bit_cast(bf16x8, *(const u16x8*)&xl[buf][ra][off]);
            }
            #pragma unroll
            for (int cf = 0; cf < 2; ++cf) {
                const int cb  = cbb + cf * 16 + (l & 15);
                const int off = (gA ^ (cb & 7)) * 8;
                Bh[cf] = __builtin_bit_cast(bf16x8, *(const u16x8*)&wh_s[buf][cb][off]);
                Bl[cf] = __builtin_bit_cast(bf16x8, *(const u16x8*)&wl_s[buf][cb][off]);
            }
            #pragma unroll
            for (int rf = 0; rf < 2; ++rf)
                #pragma unroll
                for (int cf = 0; cf < 2; ++cf) {
                    acc[rf][cf] = __builtin_amdgcn_mfma_f32_16x16x32_bf16(Ah[rf], Bh[cf], acc[rf][cf], 0, 0, 0);
                    acc[rf][cf] = __builtin_amdgcn_mfma_f32_16x16x32_bf16(Al[rf], Bh[cf], acc[rf][cf], 0, 0, 0);
                    acc[rf][cf] = __builtin_amdgcn_mfma_f32_16x16x32_bf16(Ah[rf], Bl[cf], acc[rf][cf], 0, 0, 0);
                }
        }
    };

    LOAD(0);
    for (int c = 0; c < NCHUNK; ++c) {
        STORE(c);
        if (c + 1 < NCHUNK) LOAD(c + 1);
        asm volatile("s_waitcnt lgkmcnt(0)" ::: "memory");
        __builtin_amdgcn_s_barrier();
        COMPUTE(c & 1);
    }

    #pragma unroll
    for (int rf = 0; rf < 2; ++rf)
        #pragma unroll
        for (int cf = 0; cf < 2; ++cf)
            #pragma unroll
            for (int r = 0; r < 4; ++r) {
                const int row = r0 + rbb + rf * 16 + (l >> 4) * 4 + r;
                const int col = cbb + cf * 16 + (l & 15);
                part[((size_t)blockIdx.y * MROWS + row) * 64 + col] = acc[rf][cf][r];
            }
}

// ---------------------------------------------------------------------------
// Kernel 2: reduce partials -> relu(h1) -> h2 -> gx0 (unchanged)
// ---------------------------------------------------------------------------
__global__ __launch_bounds__(256) void fc_tail(
    const float* __restrict__ part, const float* __restrict__ b0,
    const float* __restrict__ W1, const float* __restrict__ b1,
    const float* __restrict__ Wih0,
    const float* __restrict__ bih, const float* __restrict__ bhh,
    float* __restrict__ gx0)
{
    __shared__ __align__(16) float h1s[64][68];
    __shared__ __align__(16) float h2s[64][68];

    const int tid = threadIdx.x;
    const int tc  = tid & 15;
    const int tr  = tid >> 4;
    const int r0  = blockIdx.x * 64;

    {
        const int row = tid >> 2;
        const int c0  = (tid & 3) * 16;
        float4 s[4];
        #pragma unroll
        for (int i = 0; i < 4; ++i)
            s[i] = *(const float4*)(part + ((size_t)(r0 + row)) * 64 + c0 + 4 * i);
        #pragma unroll
        for (int ks = 1; ks < KS; ++ks)
            #pragma unroll
            for (int i = 0; i < 4; ++i) {
                float4 v = *(const float4*)(part + ((size_t)ks * MROWS + r0 + row) * 64 + c0 + 4 * i);
                s[i].x += v.x; s[i].y += v.y; s[i].z += v.z; s[i].w += v.w;
            }
        #pragma unroll
        for (int i = 0; i < 4; ++i) {
            float4 bv = *(const float4*)(b0 + c0 + 4 * i);
            float4 o;
            o.x = fmaxf(s[i].x + bv.x, 0.f);
            o.y = fmaxf(s[i].y + bv.y, 0.f);
            o.z = fmaxf(s[i].z + bv.z, 0.f);
            o.w = fmaxf(s[i].w + bv.w, 0.f);
            *(float4*)&h1s[row][c0 + 4 * i] = o;
        }
    }
    __syncthreads();

    float acc2[4][4] = {};
    #pragma unroll
    for (int k4 = 0; k4 < 16; ++k4) {
        const int k = k4 * 4;
        float4 a[4], wv[4];
        #pragma unroll
        for (int i = 0; i < 4; ++i) a[i] = *(const float4*)&h1s[tr * 4 + i][k];
        #pragma unroll
        for (int j = 0; j < 4; ++j) wv[j] = *(const float4*)(W1 + (size_t)(tc * 4 + j) * DIN + k);
        #pragma unroll
        for (int i = 0; i < 4; ++i)
            #pragma unroll
            for (int j = 0; j < 4; ++j)
                acc2[i][j] += a[i].x * wv[j].x + a[i].y * wv[j].y + a[i].z * wv[j].z + a[i].w * wv[j].w;
    }
    __syncthreads();
    #pragma unroll
    for (int i = 0; i < 4; ++i)
        #pragma unroll
        for (int j = 0; j < 4; ++j)
            h2s[tr * 4 + i][tc * 4 + j] = acc2[i][j] + b1[tc * 4 + j];
    __syncthreads();

    #pragma unroll
    for (int p = 0; p < 2; ++p) {
        float acc3[4][4] = {};
        #pragma unroll
        for (int k4 = 0; k4 < 16; ++k4) {
            const int k = k4 * 4;
            float4 a[4], wv[4];
            #pragma unroll
            for (int i = 0; i < 4; ++i) a[i] = *(const float4*)&h2s[tr * 4 + i][k];
            #pragma unroll
            for (int j = 0; j < 4; ++j) wv[j] = *(const float4*)(Wih0 + (size_t)(p * 64 + tc * 4 + j) * DIN + k);
            #pragma unroll
            for (int i = 0; i < 4; ++i)
                #pragma unroll
                for (int j = 0; j < 4; ++j)
                    acc3[i][j] += a[i].x * wv[j].x + a[i].y * wv[j].y + a[i].z * wv[j].z + a[i].w * wv[j].w;
        }
        const int g0 = p * 64 + tc * 4;
        #pragma unroll
        for (int i = 0; i < 4; ++i) {
            float4 ov;
            ov.x = acc3[i][0] + bih[g0 + 0] + bhh[g0 + 0];
            ov.y = acc3[i][1] + bih[g0 + 1] + bhh[g0 + 1];
            ov.z = acc3[i][2] + bih[g0 + 2] + bhh[g0 + 2];
            ov.w = acc3[i][3] + bih[g0 + 3] + bhh[g0 + 3];
            *(float4*)(gx0 + (size_t)(r0 + tr * 4 + i) * G4 + g0) = ov;
        }
    }
}

// ---------------------------------------------------------------------------
// Kernel 3: wavefront-pipelined LSTM (r2 sync structure: one timestep per
// superstep, plain __syncthreads). Round-5 changes, arithmetic-local only:
//  - weights loaded ONCE as packed float2 and PINNED in VGPRs via empty asm
//    (r2's VGPR=92 proved the compiler was re-loading weights every superstep)
//  - packed float2 accumulators -> v_pk_fma_f32 (half the FMA issue)
//  - shfl_xor(32) gate redistribution (r3-proven correct; removes gbuf LDS)
// ---------------------------------------------------------------------------
__global__ __launch_bounds__(512, 2) void lstm_all(
    const float* __restrict__ gx0,
    const float* __restrict__ Wih, const float* __restrict__ Whh,
    const float* __restrict__ bih, const float* __restrict__ bhh,
    const float* __restrict__ Wfc1, const float* __restrict__ bfc1,
    const float* __restrict__ Wfc2, const float* __restrict__ bfc2,
    float* __restrict__ out)
{
    const int b    = blockIdx.x;
    const int tid  = threadIdx.x;
    const int l    = tid >> 6;
    const int lane = tid & 63;
    const int q0   = lane;         // gate rows owned: q0, q1
    const int q1   = lane + 64;

    __shared__ __align__(16) float hbuf[NL][2][HS];  // [layer][t parity][h]
    __shared__ __align__(16) float h7[TT][HS];
    __shared__ float red[NL];

    // ---- packed weights: w2[k] = {W[q0][k], W[q1][k]} ----
    float2 whh2[HS], wih2[HS];
    {
        const float* whhl = Whh + (size_t)l * G4 * HS;
        const float* wihl = Wih + (size_t)(l > 0 ? l - 1 : 0) * G4 * HS;
        #pragma unroll
        for (int k = 0; k < HS; k += 4) {
            float4 a0 = *(const float4*)(whhl + q0 * HS + k);
            float4 a1 = *(const float4*)(whhl + q1 * HS + k);
            whh2[k+0] = make_float2(a0.x, a1.x);
            whh2[k+1] = make_float2(a0.y, a1.y);
            whh2[k+2] = make_float2(a0.z, a1.z);
            whh2[k+3] = make_float2(a0.w, a1.w);
            float4 u0 = *(const float4*)(wihl + q0 * HS + k);
            float4 u1 = *(const float4*)(wihl + q1 * HS + k);
            wih2[k+0] = make_float2(u0.x, u1.x);
            wih2[k+1] = make_float2(u0.y, u1.y);
            wih2[k+2] = make_float2(u0.z, u1.z);
            wih2[k+3] = make_float2(u0.w, u1.w);
        }
    }
    // pin weights in VGPRs: values become asm-defined -> not rematerializable
    #pragma unroll
    for (int k = 0; k < HS; ++k) {
        asm volatile("" : "+v"(whh2[k].x), "+v"(whh2[k].y),
                          "+v"(wih2[k].x), "+v"(wih2[k].y));
    }

    float2 bias2 = (l > 0)
        ? make_float2(bih[l*G4 + q0] + bhh[l*G4 + q0], bih[l*G4 + q1] + bhh[l*G4 + q1])
        : make_float2(0.f, 0.f);
    asm volatile("" : "+v"(bias2.x), "+v"(bias2.y));

    float c_state = 0.f;   // all 64 lanes; unit m = lane & 31 (redundant halves)

    const float* gxb = gx0 + (size_t)b * TT * G4;
    float2 pf = make_float2(0.f, 0.f);
    if (l == 0) pf = make_float2(gxb[q0], gxb[q1]);

    for (int s = 0; s < TT + NL - 1; ++s) {
        const int t = s - l;            // wave-uniform
        if (0 <= t && t < TT) {
            float2 g;
            if (l == 0) {
                g = pf;
                const int tn = t + 1;
                if (tn < TT) pf = make_float2(gxb[(size_t)tn * G4 + q0],
                                              gxb[(size_t)tn * G4 + q1]);
            } else {
                g = bias2;
            }
            // recurrent and input matvecs, 2 packed accumulators each
            float2 R[2] = {make_float2(0,0), make_float2(0,0)};
            float2 P[2] = {make_float2(0,0), make_float2(0,0)};
            if (t > 0) {
                const float4* hp = (const float4*)hbuf[l][(t - 1) & 1];
                #pragma unroll
                for (int k4 = 0; k4 < 8; ++k4) {
                    float4 v = hp[k4];
                    R[0] = pkfma(whh2[4*k4+0], v.x, R[0]);
                    R[1] = pkfma(whh2[4*k4+1], v.y, R[1]);
                    R[0] = pkfma(whh2[4*k4+2], v.z, R[0]);
                    R[1] = pkfma(whh2[4*k4+3], v.w, R[1]);
                }
            }
            if (l > 0) {
                const float4* hq = (const float4*)hbuf[l - 1][t & 1];
                #pragma unroll
                for (int k4 = 0; k4 < 8; ++k4) {
                    float4 v = hq[k4];
                    P[0] = pkfma(wih2[4*k4+0], v.x, P[0]);
                    P[1] = pkfma(wih2[4*k4+1], v.y, P[1]);
                    P[0] = pkfma(wih2[4*k4+2], v.z, P[0]);
                    P[1] = pkfma(wih2[4*k4+3], v.w, P[1]);
                }
            }
            const float2 gate = add2(add2(R[0], R[1]), add2(g, add2(P[0], P[1])));

            // redistribute: lane m has {i,g}; lane m+32 has {f,o}
            const float sw0 = __shfl_xor(gate.x, 32, 64);
            const float sw1 = __shfl_xor(gate.y, 32, 64);
            const bool lo = (lane < 32);
            const float gi = lo ? gate.x : sw0;
            const float gf = lo ? sw0 : gate.x;
            const float gg = lo ? gate.y : sw1;
            const float go = lo ? sw1 : gate.y;

            c_state = sigm(gf) * c_state + sigm(gi) * tanh_f(gg);
            const float hv = sigm(go) * tanh_f(c_state);

            if (lane < HS) {
                hbuf[l][t & 1][lane] = hv;
                if (l == NL - 1) h7[t][lane] = hv;
            }
        }
        __syncthreads();
    }

    // ---- fused fc1 (over H) + fc2 (over T) ----
    float part = 0.f;
    for (int t = tid; t < TT; t += 512) {
        float st = 0.f;
        #pragma unroll
        for (int j = 0; j < HS; ++j) st = fmaf(h7[t][j], Wfc1[j], st);
        part += (st + bfc1[0]) * Wfc2[t];
    }
    #pragma unroll
    for (int off = 32; off >= 1; off >>= 1) part += __shfl_down(part, off, 64);
    if (lane == 0) red[l] = part;
    __syncthreads();
    if (tid == 0) {
        float tot = 0.f;
        #pragma unroll
        for (int w = 0; w < NL; ++w) tot += red[w];
        out[b] = tot + bfc2[0];
    }
}

// ---------------------------------------------------------------------------
extern "C" void kernel_launch(void* const* d_in, const int* in_sizes, int n_in,
                              void* d_out, int out_size, void* d_ws, size_t ws_size,
                              hipStream_t stream) {
    const float* x    = (const float*)d_in[0];
    const float* W0   = (const float*)d_in[1];
    const float* b0   = (const float*)d_in[2];
    const float* W1   = (const float*)d_in[3];
    const float* b1   = (const float*)d_in[4];
    const float* Wih0 = (const float*)d_in[5];
    const float* Wih  = (const float*)d_in[6];
    const float* Whh  = (const float*)d_in[7];
    const float* bih  = (const float*)d_in[8];
    const float* bhh  = (const float*)d_in[9];
    const float* Wfc1 = (const float*)d_in[10];
    const float* bfc1 = (const float*)d_in[11];
    const float* Wfc2 = (const float*)d_in[12];
    const float* bfc2 = (const float*)d_in[13];

    char* wsb = (char*)d_ws;
    float*          gx0 = (float*)wsb;                                   // 9,830,400 B
    unsigned short* wh  = (unsigned short*)(wsb + 9830400);              //   524,288 B
    unsigned short* wl  = (unsigned short*)(wsb + 9830400 + 524288);     //   524,288 B
    float*          prt = (float*)(wsb + 9830400 + 1048576);             // 19,660,800 B

    w0split <<<256, 256, 0, stream>>>(W0, wh, wl);
    fc_gemm1<<<dim3(MROWS / 64, KS), 256, 0, stream>>>(x, wh, wl, prt);
    fc_tail <<<MROWS / 64, 256, 0, stream>>>(prt, b0, W1, b1, Wih0, bih, bhh, gx0);
    lstm_all<<<BB, 512, 0, stream>>>(gx0, Wih, Whh, bih, bhh, Wfc1, bfc1, Wfc2, bfc2,
                                     (float*)d_out);
}

// Round 6
// 473.755 us; speedup vs baseline: 1.1078x; 1.0022x over previous
//
#include <hip/hip_runtime.h>
#include <cstdint>

#define FEAT 4096
#define DIN  64
#define HS   32
#define NL   8
#define TT   300
#define BB   64
#define G4   128           // 4*HS
#define MROWS (BB*TT)      // 19200
#define KS    4            // K-split for big GEMM
#define KSLICE (FEAT/KS)   // 1024
#define BK    64
#define NCHUNK (KSLICE/BK) // 16

typedef __bf16 bf16x8 __attribute__((ext_vector_type(8)));
typedef float  f32x4  __attribute__((ext_vector_type(4)));
typedef unsigned short u16x8 __attribute__((ext_vector_type(8)));

__device__ __forceinline__ float sigm(float x){ return __fdividef(1.f, 1.f + __expf(-x)); }
__device__ __forceinline__ float tanh_f(float x){ return __fdividef(2.f, 1.f + __expf(-2.f*x)) - 1.f; }

__device__ __forceinline__ float2 pkfma(float2 w, float h, float2 c){
    return make_float2(fmaf(w.x, h, c.x), fmaf(w.y, h, c.y));
}
__device__ __forceinline__ float2 add2(float2 a, float2 b){
    return make_float2(a.x + b.x, a.y + b.y);
}

__device__ __forceinline__ unsigned short bf16_rne(float f){
    uint32_t u = __float_as_uint(f);
    return (unsigned short)((u + 0x7FFFu + ((u >> 16) & 1u)) >> 16);
}

// ---------------------------------------------------------------------------
// Prep: split W0 [64][4096] fp32 into bf16 hi/lo planes (RNE + residual).
// ---------------------------------------------------------------------------
__global__ __launch_bounds__(256) void w0split(const float* __restrict__ W0,
                                               unsigned short* __restrict__ wh,
                                               unsigned short* __restrict__ wl)
{
    const int i = (blockIdx.x * 256 + threadIdx.x) * 4;
    float4 v = *(const float4*)(W0 + i);
    float f[4] = {v.x, v.y, v.z, v.w};
    unsigned short hh[4], ll[4];
    #pragma unroll
    for (int j = 0; j < 4; ++j) {
        unsigned short h = bf16_rne(f[j]);
        float fh = __uint_as_float((uint32_t)h << 16);
        hh[j] = h;
        ll[j] = bf16_rne(f[j] - fh);
    }
    *(ushort4*)(wh + i) = make_ushort4(hh[0], hh[1], hh[2], hh[3]);
    *(ushort4*)(wl + i) = make_ushort4(ll[0], ll[1], ll[2], ll[3]);
}

// ---------------------------------------------------------------------------
// Kernel 1: h1pre partials = x @ W0^T, bf16x3-split MFMA, split-K. (unchanged)
// ---------------------------------------------------------------------------
__global__ __launch_bounds__(256, 2) void fc_gemm1(
    const float* __restrict__ x,
    const unsigned short* __restrict__ wh,
    const unsigned short* __restrict__ wl,
    float* __restrict__ part)
{
    __shared__ __align__(16) unsigned short xh[2][64][64];
    __shared__ __align__(16) unsigned short xl[2][64][64];
    __shared__ __align__(16) unsigned short wh_s[2][64][64];
    __shared__ __align__(16) unsigned short wl_s[2][64][64];

    const int t   = threadIdx.x;
    const int l   = t & 63;
    const int w   = t >> 6;
    const int rbb = (w >> 1) * 32;
    const int cbb = (w & 1) * 32;
    const int r0  = blockIdx.x * 64;
    const int kb0 = blockIdx.y * KSLICE;

    const int srow = t >> 3;
    const int sg   = t & 7;

    f32x4 acc[2][2];
    #pragma unroll
    for (int i = 0; i < 2; ++i)
        #pragma unroll
        for (int j = 0; j < 2; ++j)
            acc[i][j] = (f32x4){0.f, 0.f, 0.f, 0.f};

    float4 xr[2][2];
    uint4  w0h[2], w0l[2];

    auto LOAD = [&](int c) {
        const float* xb = x + (size_t)r0 * FEAT + kb0 + c * BK;
        xr[0][0] = *(const float4*)(xb + (size_t)srow * FEAT + sg * 8);
        xr[0][1] = *(const float4*)(xb + (size_t)srow * FEAT + sg * 8 + 4);
        xr[1][0] = *(const float4*)(xb + (size_t)(srow + 32) * FEAT + sg * 8);
        xr[1][1] = *(const float4*)(xb + (size_t)(srow + 32) * FEAT + sg * 8 + 4);
        const int wo = kb0 + c * BK + sg * 8;
        w0h[0] = *(const uint4*)(wh + (size_t)srow * FEAT + wo);
        w0h[1] = *(const uint4*)(wh + (size_t)(srow + 32) * FEAT + wo);
        w0l[0] = *(const uint4*)(wl + (size_t)srow * FEAT + wo);
        w0l[1] = *(const uint4*)(wl + (size_t)(srow + 32) * FEAT + wo);
    };

    auto STORE = [&](int c) {
        const int buf = c & 1;
        #pragma unroll
        for (int j = 0; j < 2; ++j) {
            const int row = srow + j * 32;
            const int gsw = (sg ^ (row & 7)) * 8;
            float f0[8] = {xr[j][0].x, xr[j][0].y, xr[j][0].z, xr[j][0].w,
                           xr[j][1].x, xr[j][1].y, xr[j][1].z, xr[j][1].w};
            u16x8 vh, vl;
            #pragma unroll
            for (int i = 0; i < 8; ++i) {
                uint32_t u  = __float_as_uint(f0[i]);
                uint32_t rh = (u + 0x7FFFu + ((u >> 16) & 1u)) >> 16;
                vh[i] = (unsigned short)rh;
                float fl = f0[i] - __uint_as_float(rh << 16);
                uint32_t u2 = __float_as_uint(fl);
                vl[i] = (unsigned short)((u2 + 0x7FFFu + ((u2 >> 16) & 1u)) >> 16);
            }
            *(u16x8*)&xh[buf][row][gsw] = vh;
            *(u16x8*)&xl[buf][row][gsw] = vl;
            *(uint4*)&wh_s[buf][row][gsw] = w0h[j];
            *(uint4*)&wl_s[buf][row][gsw] = w0l[j];
        }
    };

    auto COMPUTE = [&](int buf) {
        #pragma unroll
        for (int kstep = 0; kstep < 2; ++kstep) {
            const int gA = kstep * 4 + (l >> 4);
            bf16x8 Ah[2], Al[2], Bh[2], Bl[2];
            #pragma unroll
            for (int rf = 0; rf < 2; ++rf) {
                const int ra  = rbb + rf * 16 + (l & 15);
                const int off = (gA ^ (ra & 7)) * 8;
                Ah[rf] = __builtin_bit_cast(bf16x8, *(const u16x8*)&xh[buf][ra][off]);
                Al[rf] = __builtin_bit_cast(bf16x8, *(const u16x8*)&xl[buf][ra][off]);
            }
            #pragma unroll
            for (int cf = 0; cf < 2; ++cf) {
                const int cb  = cbb + cf * 16 + (l & 15);
                const int off = (gA ^ (cb & 7)) * 8;
                Bh[cf] = __builtin_bit_cast(bf16x8, *(const u16x8*)&wh_s[buf][cb][off]);
                Bl[cf] = __builtin_bit_cast(bf16x8, *(const u16x8*)&wl_s[buf][cb][off]);
            }
            #pragma unroll
            for (int rf = 0; rf < 2; ++rf)
                #pragma unroll
                for (int cf = 0; cf < 2; ++cf) {
                    acc[rf][cf] = __builtin_amdgcn_mfma_f32_16x16x32_bf16(Ah[rf], Bh[cf], acc[rf][cf], 0, 0, 0);
                    acc[rf][cf] = __builtin_amdgcn_mfma_f32_16x16x32_bf16(Al[rf], Bh[cf], acc[rf][cf], 0, 0, 0);
                    acc[rf][cf] = __builtin_amdgcn_mfma_f32_16x16x32_bf16(Ah[rf], Bl[cf], acc[rf][cf], 0, 0, 0);
                }
        }
    };

    LOAD(0);
    for (int c = 0; c < NCHUNK; ++c) {
        STORE(c);
        if (c + 1 < NCHUNK) LOAD(c + 1);
        asm volatile("s_waitcnt lgkmcnt(0)" ::: "memory");
        __builtin_amdgcn_s_barrier();
        COMPUTE(c & 1);
    }

    #pragma unroll
    for (int rf = 0; rf < 2; ++rf)
        #pragma unroll
        for (int cf = 0; cf < 2; ++cf)
            #pragma unroll
            for (int r = 0; r < 4; ++r) {
                const int row = r0 + rbb + rf * 16 + (l >> 4) * 4 + r;
                const int col = cbb + cf * 16 + (l & 15);
                part[((size_t)blockIdx.y * MROWS + row) * 64 + col] = acc[rf][cf][r];
            }
}

// ---------------------------------------------------------------------------
// Kernel 2: reduce partials -> relu(h1) -> h2 -> gx0 (unchanged)
// ---------------------------------------------------------------------------
__global__ __launch_bounds__(256) void fc_tail(
    const float* __restrict__ part, const float* __restrict__ b0,
    const float* __restrict__ W1, const float* __restrict__ b1,
    const float* __restrict__ Wih0,
    const float* __restrict__ bih, const float* __restrict__ bhh,
    float* __restrict__ gx0)
{
    __shared__ __align__(16) float h1s[64][68];
    __shared__ __align__(16) float h2s[64][68];

    const int tid = threadIdx.x;
    const int tc  = tid & 15;
    const int tr  = tid >> 4;
    const int r0  = blockIdx.x * 64;

    {
        const int row = tid >> 2;
        const int c0  = (tid & 3) * 16;
        float4 s[4];
        #pragma unroll
        for (int i = 0; i < 4; ++i)
            s[i] = *(const float4*)(part + ((size_t)(r0 + row)) * 64 + c0 + 4 * i);
        #pragma unroll
        for (int ks = 1; ks < KS; ++ks)
            #pragma unroll
            for (int i = 0; i < 4; ++i) {
                float4 v = *(const float4*)(part + ((size_t)ks * MROWS + r0 + row) * 64 + c0 + 4 * i);
                s[i].x += v.x; s[i].y += v.y; s[i].z += v.z; s[i].w += v.w;
            }
        #pragma unroll
        for (int i = 0; i < 4; ++i) {
            float4 bv = *(const float4*)(b0 + c0 + 4 * i);
            float4 o;
            o.x = fmaxf(s[i].x + bv.x, 0.f);
            o.y = fmaxf(s[i].y + bv.y, 0.f);
            o.z = fmaxf(s[i].z + bv.z, 0.f);
            o.w = fmaxf(s[i].w + bv.w, 0.f);
            *(float4*)&h1s[row][c0 + 4 * i] = o;
        }
    }
    __syncthreads();

    float acc2[4][4] = {};
    #pragma unroll
    for (int k4 = 0; k4 < 16; ++k4) {
        const int k = k4 * 4;
        float4 a[4], wv[4];
        #pragma unroll
        for (int i = 0; i < 4; ++i) a[i] = *(const float4*)&h1s[tr * 4 + i][k];
        #pragma unroll
        for (int j = 0; j < 4; ++j) wv[j] = *(const float4*)(W1 + (size_t)(tc * 4 + j) * DIN + k);
        #pragma unroll
        for (int i = 0; i < 4; ++i)
            #pragma unroll
            for (int j = 0; j < 4; ++j)
                acc2[i][j] += a[i].x * wv[j].x + a[i].y * wv[j].y + a[i].z * wv[j].z + a[i].w * wv[j].w;
    }
    __syncthreads();
    #pragma unroll
    for (int i = 0; i < 4; ++i)
        #pragma unroll
        for (int j = 0; j < 4; ++j)
            h2s[tr * 4 + i][tc * 4 + j] = acc2[i][j] + b1[tc * 4 + j];
    __syncthreads();

    #pragma unroll
    for (int p = 0; p < 2; ++p) {
        float acc3[4][4] = {};
        #pragma unroll
        for (int k4 = 0; k4 < 16; ++k4) {
            const int k = k4 * 4;
            float4 a[4], wv[4];
            #pragma unroll
            for (int i = 0; i < 4; ++i) a[i] = *(const float4*)&h2s[tr * 4 + i][k];
            #pragma unroll
            for (int j = 0; j < 4; ++j) wv[j] = *(const float4*)(Wih0 + (size_t)(p * 64 + tc * 4 + j) * DIN + k);
            #pragma unroll
            for (int i = 0; i < 4; ++i)
                #pragma unroll
                for (int j = 0; j < 4; ++j)
                    acc3[i][j] += a[i].x * wv[j].x + a[i].y * wv[j].y + a[i].z * wv[j].z + a[i].w * wv[j].w;
        }
        const int g0 = p * 64 + tc * 4;
        #pragma unroll
        for (int i = 0; i < 4; ++i) {
            float4 ov;
            ov.x = acc3[i][0] + bih[g0 + 0] + bhh[g0 + 0];
            ov.y = acc3[i][1] + bih[g0 + 1] + bhh[g0 + 1];
            ov.z = acc3[i][2] + bih[g0 + 2] + bhh[g0 + 2];
            ov.w = acc3[i][3] + bih[g0 + 3] + bhh[g0 + 3];
            *(float4*)(gx0 + (size_t)(r0 + tr * 4 + i) * G4 + g0) = ov;
        }
    }
}

// ---------------------------------------------------------------------------
// Kernel 3: wavefront-pipelined LSTM (r2 sync structure: one timestep per
// superstep, plain __syncthreads). Round-5 changes, arithmetic-local only:
//  - weights loaded ONCE as packed float2 and PINNED in VGPRs via empty asm
//    (r2's VGPR=92 proved the compiler was re-loading weights every superstep)
//  - packed float2 accumulators -> v_pk_fma_f32 (half the FMA issue)
//  - shfl_xor(32) gate redistribution (r3-proven correct; removes gbuf LDS)
// ---------------------------------------------------------------------------
__global__ __launch_bounds__(512, 2) void lstm_all(
    const float* __restrict__ gx0,
    const float* __restrict__ Wih, const float* __restrict__ Whh,
    const float* __restrict__ bih, const float* __restrict__ bhh,
    const float* __restrict__ Wfc1, const float* __restrict__ bfc1,
    const float* __restrict__ Wfc2, const float* __restrict__ bfc2,
    float* __restrict__ out)
{
    const int b    = blockIdx.x;
    const int tid  = threadIdx.x;
    const int l    = tid >> 6;
    const int lane = tid & 63;
    const int q0   = lane;         // gate rows owned: q0, q1
    const int q1   = lane + 64;

    __shared__ __align__(16) float hbuf[NL][2][HS];  // [layer][t parity][h]
    __shared__ __align__(16) float h7[TT][HS];
    __shared__ float red[NL];

    // ---- packed weights: w2[k] = {W[q0][k], W[q1][k]} ----
    float2 whh2[HS], wih2[HS];
    {
        const float* whhl = Whh + (size_t)l * G4 * HS;
        const float* wihl = Wih + (size_t)(l > 0 ? l - 1 : 0) * G4 * HS;
        #pragma unroll
        for (int k = 0; k < HS; k += 4) {
            float4 a0 = *(const float4*)(whhl + q0 * HS + k);
            float4 a1 = *(const float4*)(whhl + q1 * HS + k);
            whh2[k+0] = make_float2(a0.x, a1.x);
            whh2[k+1] = make_float2(a0.y, a1.y);
            whh2[k+2] = make_float2(a0.z, a1.z);
            whh2[k+3] = make_float2(a0.w, a1.w);
            float4 u0 = *(const float4*)(wihl + q0 * HS + k);
            float4 u1 = *(const float4*)(wihl + q1 * HS + k);
            wih2[k+0] = make_float2(u0.x, u1.x);
            wih2[k+1] = make_float2(u0.y, u1.y);
            wih2[k+2] = make_float2(u0.z, u1.z);
            wih2[k+3] = make_float2(u0.w, u1.w);
        }
    }
    // pin weights in VGPRs: values become asm-defined -> not rematerializable
    #pragma unroll
    for (int k = 0; k < HS; ++k) {
        asm volatile("" : "+v"(whh2[k].x), "+v"(whh2[k].y),
                          "+v"(wih2[k].x), "+v"(wih2[k].y));
    }

    float2 bias2 = (l > 0)
        ? make_float2(bih[l*G4 + q0] + bhh[l*G4 + q0], bih[l*G4 + q1] + bhh[l*G4 + q1])
        : make_float2(0.f, 0.f);
    asm volatile("" : "+v"(bias2.x), "+v"(bias2.y));

    float c_state = 0.f;   // all 64 lanes; unit m = lane & 31 (redundant halves)

    const float* gxb = gx0 + (size_t)b * TT * G4;
    float2 pf = make_float2(0.f, 0.f);
    if (l == 0) pf = make_float2(gxb[q0], gxb[q1]);

    for (int s = 0; s < TT + NL - 1; ++s) {
        const int t = s - l;            // wave-uniform
        if (0 <= t && t < TT) {
            float2 g;
            if (l == 0) {
                g = pf;
                const int tn = t + 1;
                if (tn < TT) pf = make_float2(gxb[(size_t)tn * G4 + q0],
                                              gxb[(size_t)tn * G4 + q1]);
            } else {
                g = bias2;
            }
            // recurrent and input matvecs, 2 packed accumulators each
            float2 R[2] = {make_float2(0,0), make_float2(0,0)};
            float2 P[2] = {make_float2(0,0), make_float2(0,0)};
            if (t > 0) {
                const float4* hp = (const float4*)hbuf[l][(t - 1) & 1];
                #pragma unroll
                for (int k4 = 0; k4 < 8; ++k4) {
                    float4 v = hp[k4];
                    R[0] = pkfma(whh2[4*k4+0], v.x, R[0]);
                    R[1] = pkfma(whh2[4*k4+1], v.y, R[1]);
                    R[0] = pkfma(whh2[4*k4+2], v.z, R[0]);
                    R[1] = pkfma(whh2[4*k4+3], v.w, R[1]);
                }
            }
            if (l > 0) {
                const float4* hq = (const float4*)hbuf[l - 1][t & 1];
                #pragma unroll
                for (int k4 = 0; k4 < 8; ++k4) {
                    float4 v = hq[k4];
                    P[0] = pkfma(wih2[4*k4+0], v.x, P[0]);
                    P[1] = pkfma(wih2[4*k4+1], v.y, P[1]);
                    P[0] = pkfma(wih2[4*k4+2], v.z, P[0]);
                    P[1] = pkfma(wih2[4*k4+3], v.w, P[1]);
                }
            }
            const float2 gate = add2(add2(R[0], R[1]), add2(g, add2(P[0], P[1])));

            // redistribute: lane m has {i,g}; lane m+32 has {f,o}
            const float sw0 = __shfl_xor(gate.x, 32, 64);
            const float sw1 = __shfl_xor(gate.y, 32, 64);
            const bool lo = (lane < 32);
            const float gi = lo ? gate.x : sw0;
            const float gf = lo ? sw0 : gate.x;
            const float gg = lo ? gate.y : sw1;
            const float go = lo ? sw1 : gate.y;

            c_state = sigm(gf) * c_state + sigm(gi) * tanh_f(gg);
            const float hv = sigm(go) * tanh_f(c_state);

            if (lane < HS) {
                hbuf[l][t & 1][lane] = hv;
                if (l == NL - 1) h7[t][lane] = hv;
            }
        }
        __syncthreads();
    }

    // ---- fused fc1 (over H) + fc2 (over T) ----
    float part = 0.f;
    for (int t = tid; t < TT; t += 512) {
        float st = 0.f;
        #pragma unroll
        for (int j = 0; j < HS; ++j) st = fmaf(h7[t][j], Wfc1[j], st);
        part += (st + bfc1[0]) * Wfc2[t];
    }
    #pragma unroll
    for (int off = 32; off >= 1; off >>= 1) part += __shfl_down(part, off, 64);
    if (lane == 0) red[l] = part;
    __syncthreads();
    if (tid == 0) {
        float tot = 0.f;
        #pragma unroll
        for (int w = 0; w < NL; ++w) tot += red[w];
        out[b] = tot + bfc2[0];
    }
}

// ---------------------------------------------------------------------------
extern "C" void kernel_launch(void* const* d_in, const int* in_sizes, int n_in,
                              void* d_out, int out_size, void* d_ws, size_t ws_size,
                              hipStream_t stream) {
    const float* x    = (const float*)d_in[0];
    const float* W0   = (const float*)d_in[1];
    const float* b0   = (const float*)d_in[2];
    const float* W1   = (const float*)d_in[3];
    const float* b1   = (const float*)d_in[4];
    const float* Wih0 = (const float*)d_in[5];
    const float* Wih  = (const float*)d_in[6];
    const float* Whh  = (const float*)d_in[7];
    const float* bih  = (const float*)d_in[8];
    const float* bhh  = (const float*)d_in[9];
    const float* Wfc1 = (const float*)d_in[10];
    const float* bfc1 = (const float*)d_in[11];
    const float* Wfc2 = (const float*)d_in[12];
    const float* bfc2 = (const float*)d_in[13];

    char* wsb = (char*)d_ws;
    float*          gx0 = (float*)wsb;                                   // 9,830,400 B
    unsigned short* wh  = (unsigned short*)(wsb + 9830400);              //   524,288 B
    unsigned short* wl  = (unsigned short*)(wsb + 9830400 + 524288);     //   524,288 B
    float*          prt = (float*)(wsb + 9830400 + 1048576);             // 19,660,800 B

    w0split <<<256, 256, 0, stream>>>(W0, wh, wl);
    fc_gemm1<<<dim3(MROWS / 64, KS), 256, 0, stream>>>(x, wh, wl, prt);
    fc_tail <<<MROWS / 64, 256, 0, stream>>>(prt, b0, W1, b1, Wih0, bih, bhh, gx0);
    lstm_all<<<BB, 512, 0, stream>>>(gx0, Wih, Whh, bih, bhh, Wfc1, bfc1, Wfc2, bfc2,
                                     (float*)d_out);
}